// Round 1
// 1184.524 us; speedup vs baseline: 1.4875x; 1.4875x over previous
//
#include <hip/hip_runtime.h>
#include <math.h>

#define Bn   4
#define Sn   1024
#define Dn   1024
#define Hn   16
#define DKn  64
#define MRPn 1000

typedef __attribute__((ext_vector_type(8))) short short8;
typedef __attribute__((ext_vector_type(4))) float f32x4;

static __device__ __forceinline__ unsigned short f2bf(float f) {
    unsigned u = __float_as_uint(f);
    u += 0x7FFF + ((u >> 16) & 1);          // RNE
    return (unsigned short)(u >> 16);
}

// ---------------------------------------------------------------------------
// fp32 -> bf16 cast, 4 elems/thread. n must be multiple of 4 (true here).
// ---------------------------------------------------------------------------
__global__ __launch_bounds__(256) void cast_f32_bf16(
    const float* __restrict__ s, unsigned short* __restrict__ d, int n)
{
    int i = (blockIdx.x * 256 + threadIdx.x) * 4;
    if (i >= n) return;
    float4 v = *(const float4*)(s + i);
    ushort4 o;
    o.x = f2bf(v.x); o.y = f2bf(v.y); o.z = f2bf(v.z); o.w = f2bf(v.w);
    *(ushort4*)(d + i) = o;
}

// ---------------------------------------------------------------------------
// C[M,N] = A[M,K](bf16) @ W[N,K](bf16)^T + bias[N], fp32 out.
// 128x128 tile, BK=32, 4 waves, each wave 64x64 via 4x4 grid of 16x16x32 MFMA.
// ---------------------------------------------------------------------------
#define LP 40   // LDS row pitch in bf16 elems (80 B, 16B-aligned, conflict-spread)
__global__ __launch_bounds__(256) void gemm_bf16_mfma(
    const unsigned short* __restrict__ A, const unsigned short* __restrict__ W,
    const float* __restrict__ bias, float* __restrict__ C,
    int M, int N, int K)
{
    __shared__ unsigned short As[128 * LP];
    __shared__ unsigned short Bs[128 * LP];
    const int tid  = threadIdx.x;
    const int lane = tid & 63;
    const int wave = tid >> 6;
    const int m0 = blockIdx.y * 128, n0 = blockIdx.x * 128;
    const int wm = (wave & 1) * 64, wn = (wave >> 1) * 64;
    const int fr   = lane & 15;
    const int quad = lane >> 4;

    f32x4 acc[4][4];
#pragma unroll
    for (int i = 0; i < 4; ++i)
#pragma unroll
        for (int j = 0; j < 4; ++j) acc[i][j] = (f32x4){0.f, 0.f, 0.f, 0.f};

    const int srow   = tid >> 2;        // 0..63 (and +64 in pass 2)
    const int schunk = (tid & 3) * 8;   // k-element offset 0,8,16,24

    for (int kb = 0; kb < K; kb += 32) {
        const unsigned short* ga = A + (size_t)(m0 + srow) * K + kb + schunk;
        const unsigned short* gb = W + (size_t)(n0 + srow) * K + kb + schunk;
        short8 a0 = *(const short8*)ga;
        short8 a1 = *(const short8*)(ga + (size_t)64 * K);
        short8 b0 = *(const short8*)gb;
        short8 b1 = *(const short8*)(gb + (size_t)64 * K);
        __syncthreads();                 // previous iter's frag reads done
        *(short8*)&As[srow * LP + schunk]        = a0;
        *(short8*)&As[(srow + 64) * LP + schunk] = a1;
        *(short8*)&Bs[srow * LP + schunk]        = b0;
        *(short8*)&Bs[(srow + 64) * LP + schunk] = b1;
        __syncthreads();

        short8 af[4], bf[4];
#pragma unroll
        for (int mi = 0; mi < 4; ++mi)
            af[mi] = *(const short8*)&As[(wm + 16 * mi + fr) * LP + quad * 8];
#pragma unroll
        for (int ni = 0; ni < 4; ++ni)
            bf[ni] = *(const short8*)&Bs[(wn + 16 * ni + fr) * LP + quad * 8];
#pragma unroll
        for (int mi = 0; mi < 4; ++mi)
#pragma unroll
            for (int ni = 0; ni < 4; ++ni)
                acc[mi][ni] = __builtin_amdgcn_mfma_f32_16x16x32_bf16(
                    af[mi], bf[ni], acc[mi][ni], 0, 0, 0);
    }

#pragma unroll
    for (int ni = 0; ni < 4; ++ni) {
        int cc = n0 + wn + 16 * ni + fr;
        float bv = bias[cc];
#pragma unroll
        for (int mi = 0; mi < 4; ++mi) {
            int rbase = m0 + wm + 16 * mi + quad * 4;
#pragma unroll
            for (int r = 0; r < 4; ++r)
                C[(size_t)(rbase + r) * N + cc] = acc[mi][ni][r] + bv;
        }
    }
}

// ---------------------------------------------------------------------------
// logits[bh,q,k] = Q[q,:].K[k,:] + Q[q,:].embK[clip(k-q)+MRP,:]
// ---------------------------------------------------------------------------
__global__ __launch_bounds__(256) void logits_kernel(
    const float* __restrict__ Qp, const float* __restrict__ Kp,
    const float* __restrict__ embK, float* __restrict__ L)
{
    __shared__ float Qs[64][65];
    __shared__ float Ks[32][65];
    __shared__ float Es[95][65];
    const int tid = threadIdx.x;
    const int tx = tid & 15, ty = tid >> 4;
    const int bh = blockIdx.z;
    const int b = bh >> 4, h = bh & 15;
    const int q0 = blockIdx.y * 64;

    for (int i = tid; i < 64 * 64; i += 256) {
        int r = i >> 6, d = i & 63;
        Qs[r][d] = Qp[(size_t)(b * Sn + q0 + r) * Dn + h * DKn + d];
    }

    for (int half = 0; half < 2; ++half) {
        const int k0 = blockIdx.x * 64 + half * 32;
        __syncthreads();   // Qs ready / previous half's compute done
        for (int i = tid; i < 32 * 64; i += 256) {
            int r = i >> 6, d = i & 63;
            Ks[r][d] = Kp[(size_t)(b * Sn + k0 + r) * Dn + h * DKn + d];
        }
        for (int i = tid; i < 95 * 64; i += 256) {
            int r = i >> 6, d = i & 63;
            int diff = k0 - q0 - 63 + r;
            diff = min(max(diff, -MRPn), MRPn);
            Es[r][d] = embK[(size_t)(diff + MRPn) * DKn + d];
        }
        __syncthreads();

        float acc[4][2];
#pragma unroll
        for (int i = 0; i < 4; ++i) { acc[i][0] = 0.f; acc[i][1] = 0.f; }
        const int erow = tx - ty + 15;   // + 16*t

#pragma unroll 4
        for (int d = 0; d < 64; ++d) {
            float q[4], k[2], e[5];
#pragma unroll
            for (int i = 0; i < 4; ++i) q[i] = Qs[ty + 16 * i][d];
#pragma unroll
            for (int j = 0; j < 2; ++j) k[j] = Ks[tx + 16 * j][d];
#pragma unroll
            for (int t = 0; t < 5; ++t) e[t] = Es[erow + 16 * t][d];
#pragma unroll
            for (int i = 0; i < 4; ++i)
#pragma unroll
                for (int j = 0; j < 2; ++j)
                    acc[i][j] = fmaf(q[i], k[j] + e[j - i + 3], acc[i][j]);
        }

#pragma unroll
        for (int i = 0; i < 4; ++i) {
            int qq = q0 + ty + 16 * i;
#pragma unroll
            for (int j = 0; j < 2; ++j)
                L[((size_t)bh * Sn + qq) * Sn + k0 + tx + 16 * j] = acc[i][j];
        }
    }
}

// ---------------------------------------------------------------------------
// In-place row softmax over last dim (1024). One block (256 thr) per row.
// ---------------------------------------------------------------------------
__global__ __launch_bounds__(256) void softmax_kernel(float* __restrict__ Wt)
{
    __shared__ float red[4];
    const int tid = threadIdx.x;
    float* p = Wt + (size_t)blockIdx.x * Sn;
    float4 v = ((const float4*)p)[tid];

    float m = fmaxf(fmaxf(v.x, v.y), fmaxf(v.z, v.w));
#pragma unroll
    for (int o = 32; o > 0; o >>= 1) m = fmaxf(m, __shfl_down(m, o, 64));
    if ((tid & 63) == 0) red[tid >> 6] = m;
    __syncthreads();
    m = fmaxf(fmaxf(red[0], red[1]), fmaxf(red[2], red[3]));
    __syncthreads();

    float4 e;
    e.x = expf(v.x - m); e.y = expf(v.y - m);
    e.z = expf(v.z - m); e.w = expf(v.w - m);
    float s = e.x + e.y + e.z + e.w;
#pragma unroll
    for (int o = 32; o > 0; o >>= 1) s += __shfl_down(s, o, 64);
    if ((tid & 63) == 0) red[tid >> 6] = s;
    __syncthreads();
    s = red[0] + red[1] + red[2] + red[3];

    float inv = 1.0f / s;
    e.x *= inv; e.y *= inv; e.z *= inv; e.w *= inv;
    ((float4*)p)[tid] = e;
}

// ---------------------------------------------------------------------------
// Vt[bh][d][k] = bf16(Vp[b, k, h*64+d])  — transposed bf16 V for MFMA B-operand
// Block: 64k x 64d tile. Grid: (S/64, B*H).
// ---------------------------------------------------------------------------
__global__ __launch_bounds__(256) void v_transpose(
    const float* __restrict__ Vp, unsigned short* __restrict__ Vt)
{
    __shared__ float T[64][68];
    const int tid = threadIdx.x;
    const int k0 = blockIdx.x * 64;
    const int bh = blockIdx.y;
    const int b = bh >> 4, h = bh & 15;
#pragma unroll
    for (int p = 0; p < 4; ++p) {
        int kk = p * 16 + (tid >> 4);
        int dd = (tid & 15) * 4;
        float4 v = *(const float4*)&Vp[(size_t)(b * Sn + k0 + kk) * Dn + h * DKn + dd];
        *(float4*)&T[kk][dd] = v;
    }
    __syncthreads();
    const int d   = tid >> 2;
    const int kk0 = (tid & 3) * 16;
    short8 o0, o1;
#pragma unroll
    for (int e = 0; e < 8; ++e) o0[e] = (short)f2bf(T[kk0 + e][d]);
#pragma unroll
    for (int e = 0; e < 8; ++e) o1[e] = (short)f2bf(T[kk0 + 8 + e][d]);
    unsigned short* dst = Vt + ((size_t)bh * DKn + d) * Sn + k0 + kk0;
    *(short8*)dst       = o0;
    *(short8*)(dst + 8) = o1;
}

// ---------------------------------------------------------------------------
// E2V[d][u] = bf16(embV[clip(u-1024,-MRP,MRP)+MRP, d]), u in [0,2048)
// Transposed (d-major) so it can be a GEMM B-operand. 64 blocks x 256 thr x 8.
// ---------------------------------------------------------------------------
__global__ __launch_bounds__(256) void build_e2v(
    const float* __restrict__ embV, unsigned short* __restrict__ E2V)
{
    int i = (blockIdx.x * 256 + threadIdx.x) * 8;   // < 64*2048
    int d = i >> 11, u0 = i & 2047;
    short8 o;
#pragma unroll
    for (int e = 0; e < 8; ++e) {
        int t = u0 + e - 1024;
        t = min(max(t, -MRPn), MRPn);
        o[e] = (short)f2bf(embV[(size_t)(t + MRPn) * DKn + d]);
    }
    *(short8*)&E2V[i] = o;
}

// ---------------------------------------------------------------------------
// MFMA AV: X[b,q,h*64+d] = sum_k W[bh,q,k]*V[k,d] + sum_u Wsk[q,u]*E2V[u,d]
// where Wsk[q,u] = W[bh,q,q+u-1024] (0 if OOB), u = k-q+1024.
// Each W element maps to exactly one u-slot, so phase 2 is an exact skew-GEMM.
// Block: 64q x 64d for one bh; 4 waves, each 32x32 via 2x2 of 16x16x32 MFMA.
// Phase 1: K=1024 over V. Phase 2: ~34 non-empty u-steps over E2V.
// A (W, fp32) converted to bf16 during LDS staging.
// ---------------------------------------------------------------------------
__global__ __launch_bounds__(256) void av_mfma(
    const float* __restrict__ Wt, const unsigned short* __restrict__ Vt,
    const unsigned short* __restrict__ E2V, unsigned short* __restrict__ Xbf)
{
    __shared__ unsigned short As[64 * LP];
    __shared__ unsigned short Bs[64 * LP];
    const int tid  = threadIdx.x;
    const int lane = tid & 63;
    const int wave = tid >> 6;
    const int q0 = blockIdx.x * 64;
    const int bh = blockIdx.y;
    const int b = bh >> 4, h = bh & 15;
    const int wm = (wave & 1) * 32;      // q offset within tile
    const int wn = (wave >> 1) * 32;     // d offset within tile
    const int fr = lane & 15, quad = lane >> 4;

    const float* Wrow = Wt + (size_t)bh * Sn * Sn;   // [S][S] fp32 weights

    f32x4 acc[2][2];
#pragma unroll
    for (int i = 0; i < 2; ++i)
#pragma unroll
        for (int j = 0; j < 2; ++j) acc[i][j] = (f32x4){0.f, 0.f, 0.f, 0.f};

    const int ar = tid >> 3;          // 0..31 (+32 for pass 1)
    const int ac = (tid & 7) * 4;     // 0,4,...,28
    const int br = tid >> 2;          // 0..63
    const int bc = (tid & 3) * 8;     // 0,8,16,24

    const unsigned short* vrow = Vt + ((size_t)bh * DKn + br) * Sn;

    // ---- phase 1: W @ V^T  (K = 1024) ----
    for (int kb = 0; kb < Sn; kb += 32) {
        short8 bv = *(const short8*)(vrow + kb + bc);
        float4 a0 = *(const float4*)&Wrow[(size_t)(q0 + ar) * Sn + kb + ac];
        float4 a1 = *(const float4*)&Wrow[(size_t)(q0 + ar + 32) * Sn + kb + ac];
        __syncthreads();                 // previous iter's frag reads done
        ushort4 s0, s1;
        s0.x = f2bf(a0.x); s0.y = f2bf(a0.y); s0.z = f2bf(a0.z); s0.w = f2bf(a0.w);
        s1.x = f2bf(a1.x); s1.y = f2bf(a1.y); s1.z = f2bf(a1.z); s1.w = f2bf(a1.w);
        *(ushort4*)&As[ar * LP + ac]        = s0;
        *(ushort4*)&As[(ar + 32) * LP + ac] = s1;
        *(short8*)&Bs[br * LP + bc]         = bv;
        __syncthreads();

        short8 af[2], bfv[2];
#pragma unroll
        for (int mi = 0; mi < 2; ++mi)
            af[mi] = *(const short8*)&As[(wm + 16 * mi + fr) * LP + quad * 8];
#pragma unroll
        for (int ni = 0; ni < 2; ++ni)
            bfv[ni] = *(const short8*)&Bs[(wn + 16 * ni + fr) * LP + quad * 8];
#pragma unroll
        for (int mi = 0; mi < 2; ++mi)
#pragma unroll
            for (int ni = 0; ni < 2; ++ni)
                acc[mi][ni] = __builtin_amdgcn_mfma_f32_16x16x32_bf16(
                    af[mi], bfv[ni], acc[mi][ni], 0, 0, 0);
    }

    // ---- phase 2: Wsk @ E2V^T (skewed gather of W, only non-empty u-steps) --
    int lo = 1024 - q0 - 63; if (lo < 0) lo = 0; lo &= ~31;
    const int hi = 2047 - q0;            // inclusive max u
    for (int ub = lo; ub <= hi; ub += 32) {
        short8 bv = *(const short8*)&E2V[(size_t)br * 2048 + ub + bc];
        float fa[2][4];
#pragma unroll
        for (int p = 0; p < 2; ++p) {
            int q = q0 + ar + 32 * p;
            int k = q + ub + ac - 1024;
#pragma unroll
            for (int e = 0; e < 4; ++e) {
                int ke = k + e;
                fa[p][e] = ((unsigned)ke < 1024u) ? Wrow[(size_t)q * Sn + ke] : 0.f;
            }
        }
        __syncthreads();
        ushort4 s0, s1;
        s0.x = f2bf(fa[0][0]); s0.y = f2bf(fa[0][1]);
        s0.z = f2bf(fa[0][2]); s0.w = f2bf(fa[0][3]);
        s1.x = f2bf(fa[1][0]); s1.y = f2bf(fa[1][1]);
        s1.z = f2bf(fa[1][2]); s1.w = f2bf(fa[1][3]);
        *(ushort4*)&As[ar * LP + ac]        = s0;
        *(ushort4*)&As[(ar + 32) * LP + ac] = s1;
        *(short8*)&Bs[br * LP + bc]         = bv;
        __syncthreads();

        short8 af[2], bfv[2];
#pragma unroll
        for (int mi = 0; mi < 2; ++mi)
            af[mi] = *(const short8*)&As[(wm + 16 * mi + fr) * LP + quad * 8];
#pragma unroll
        for (int ni = 0; ni < 2; ++ni)
            bfv[ni] = *(const short8*)&Bs[(wn + 16 * ni + fr) * LP + quad * 8];
#pragma unroll
        for (int mi = 0; mi < 2; ++mi)
#pragma unroll
            for (int ni = 0; ni < 2; ++ni)
                acc[mi][ni] = __builtin_amdgcn_mfma_f32_16x16x32_bf16(
                    af[mi], bfv[ni], acc[mi][ni], 0, 0, 0);
    }

    // ---- epilogue: write X as bf16 for the Wo GEMM ----
#pragma unroll
    for (int ni = 0; ni < 2; ++ni) {
        int d = wn + 16 * ni + fr;
#pragma unroll
        for (int mi = 0; mi < 2; ++mi) {
            int qb = q0 + wm + 16 * mi + quad * 4;
#pragma unroll
            for (int r = 0; r < 4; ++r)
                Xbf[(size_t)(b * Sn + qb + r) * Dn + h * DKn + d] =
                    f2bf(acc[mi][ni][r]);
        }
    }
}

// ---------------------------------------------------------------------------
extern "C" void kernel_launch(void* const* d_in, const int* in_sizes, int n_in,
                              void* d_out, int out_size, void* d_ws, size_t ws_size,
                              hipStream_t stream)
{
    const float* query = (const float*)d_in[0];
    const float* key   = (const float*)d_in[1];
    const float* value = (const float*)d_in[2];
    const float* Wq    = (const float*)d_in[3];
    const float* bq    = (const float*)d_in[4];
    const float* Wk    = (const float*)d_in[5];
    const float* bk    = (const float*)d_in[6];
    const float* Wv    = (const float*)d_in[7];
    const float* bv    = (const float*)d_in[8];
    const float* Wo    = (const float*)d_in[9];
    const float* bo    = (const float*)d_in[10];
    const float* embK  = (const float*)d_in[11];
    const float* embV  = (const float*)d_in[12];

    const size_t NTOK = (size_t)Bn * Sn;          // 4096
    const size_t PROJ = NTOK * Dn;                // 4,194,304
    const size_t WSZ  = (size_t)Dn * Dn;          // 1,048,576

    float* ws  = (float*)d_ws;
    float* Q   = ws;                              // fp32 [4096,1024]
    float* Kp  = ws + PROJ;
    float* Vp  = ws + 2 * PROJ;
    unsigned short* Abf = (unsigned short*)(ws + 3 * PROJ);  // bf16 [4096,1024]
    unsigned short* Wqb = Abf + PROJ;
    unsigned short* Wkb = Wqb + WSZ;
    unsigned short* Wvb = Wkb + WSZ;
    unsigned short* Wob = Wvb + WSZ;
    unsigned short* Vtb = Wob + WSZ;              // bf16 [64bh][64d][1024k] = 8 MB
    unsigned short* E2V = Vtb + (size_t)Bn * Hn * DKn * Sn;  // bf16 [64][2048]

    float* outp = (float*)d_out;                  // [B,S,D]
    float* Wt   = outp + PROJ;                    // weights [B,H,S,S]

    const int CAST_W_GRID = (int)(WSZ / 4 / 256);
    const int CAST_A_GRID = (int)(PROJ / 4 / 256);
    dim3 gemmGrid(Dn / 128, (int)(NTOK / 128));   // (8, 32)

    build_e2v<<<64, 256, 0, stream>>>(embV, E2V);

    cast_f32_bf16<<<CAST_W_GRID, 256, 0, stream>>>(Wq, Wqb, (int)WSZ);
    cast_f32_bf16<<<CAST_W_GRID, 256, 0, stream>>>(Wk, Wkb, (int)WSZ);
    cast_f32_bf16<<<CAST_W_GRID, 256, 0, stream>>>(Wv, Wvb, (int)WSZ);
    cast_f32_bf16<<<CAST_W_GRID, 256, 0, stream>>>(Wo, Wob, (int)WSZ);

    cast_f32_bf16<<<CAST_A_GRID, 256, 0, stream>>>(query, Abf, (int)PROJ);
    gemm_bf16_mfma<<<gemmGrid, 256, 0, stream>>>(Abf, Wqb, bq, Q,  (int)NTOK, Dn, Dn);
    cast_f32_bf16<<<CAST_A_GRID, 256, 0, stream>>>(key, Abf, (int)PROJ);
    gemm_bf16_mfma<<<gemmGrid, 256, 0, stream>>>(Abf, Wkb, bk, Kp, (int)NTOK, Dn, Dn);
    cast_f32_bf16<<<CAST_A_GRID, 256, 0, stream>>>(value, Abf, (int)PROJ);
    gemm_bf16_mfma<<<gemmGrid, 256, 0, stream>>>(Abf, Wvb, bv, Vp, (int)NTOK, Dn, Dn);

    v_transpose<<<dim3(Sn / 64, Bn * Hn), 256, 0, stream>>>(Vp, Vtb);

    logits_kernel<<<dim3(Sn / 64, Sn / 64, Bn * Hn), 256, 0, stream>>>(Q, Kp, embK, Wt);

    softmax_kernel<<<Bn * Hn * Sn, 256, 0, stream>>>(Wt);

    av_mfma<<<dim3(Sn / 64, Bn * Hn), 256, 0, stream>>>(Wt, Vtb, E2V, Abf);

    gemm_bf16_mfma<<<gemmGrid, 256, 0, stream>>>(Abf, Wob, bo, outp, (int)NTOK, Dn, Dn);
}

// Round 2
// 889.983 us; speedup vs baseline: 1.9798x; 1.3310x over previous
//
#include <hip/hip_runtime.h>
#include <math.h>

#define Bn   4
#define Sn   1024
#define Dn   1024
#define Hn   16
#define DKn  64
#define MRPn 1000
#define RKU  2049   // u in [0,2048]; row 2048 is an OOB-pad (band over-read, never gathered)

typedef __attribute__((ext_vector_type(8))) short short8;
typedef __attribute__((ext_vector_type(4))) float f32x4;

static __device__ __forceinline__ unsigned short f2bf(float f) {
    unsigned u = __float_as_uint(f);
    u += 0x7FFF + ((u >> 16) & 1);          // RNE
    return (unsigned short)(u >> 16);
}
static __device__ __forceinline__ float bf2f(unsigned short h) {
    return __uint_as_float((unsigned)h << 16);
}

// ---------------------------------------------------------------------------
// fp32 -> bf16 cast, 4 elems/thread.
// ---------------------------------------------------------------------------
__global__ __launch_bounds__(256) void cast_f32_bf16(
    const float* __restrict__ s, unsigned short* __restrict__ d, int n)
{
    int i = (blockIdx.x * 256 + threadIdx.x) * 4;
    if (i >= n) return;
    float4 v = *(const float4*)(s + i);
    ushort4 o;
    o.x = f2bf(v.x); o.y = f2bf(v.y); o.z = f2bf(v.z); o.w = f2bf(v.w);
    *(ushort4*)(d + i) = o;
}

// ---------------------------------------------------------------------------
// C = A[M,K](bf16) @ W[N,K](bf16)^T + bias[N].
// mode 0: fp32 out C[M,N].
// mode 1: split bf16 out, head layout: Chi/Clo[((b*16+h)*1024+q)*64+d]
//         (hi = bf16(val), lo = bf16(val-hi)) for fp32-accurate MFMA later.
// mode 2: bf16 transposed head layout: Chi[((b*16+h)*64+d)*1024+tok]  (V^T).
// 128x128 tile, BK=32, 4 waves of 64x64 (4x4 of 16x16x32 MFMA).
// ---------------------------------------------------------------------------
#define LP 40   // LDS row pitch in bf16 elems
__global__ __launch_bounds__(256) void gemm_bf16_mfma(
    const unsigned short* __restrict__ A, const unsigned short* __restrict__ W,
    const float* __restrict__ bias, float* __restrict__ C,
    unsigned short* __restrict__ Chi, unsigned short* __restrict__ Clo,
    int M, int N, int K, int mode)
{
    __shared__ unsigned short As[128 * LP];
    __shared__ unsigned short Bs[128 * LP];
    const int tid  = threadIdx.x;
    const int lane = tid & 63;
    const int wave = tid >> 6;
    const int m0 = blockIdx.y * 128, n0 = blockIdx.x * 128;
    const int wm = (wave & 1) * 64, wn = (wave >> 1) * 64;
    const int fr   = lane & 15;
    const int quad = lane >> 4;

    f32x4 acc[4][4];
#pragma unroll
    for (int i = 0; i < 4; ++i)
#pragma unroll
        for (int j = 0; j < 4; ++j) acc[i][j] = (f32x4){0.f, 0.f, 0.f, 0.f};

    const int srow   = tid >> 2;
    const int schunk = (tid & 3) * 8;

    for (int kb = 0; kb < K; kb += 32) {
        const unsigned short* ga = A + (size_t)(m0 + srow) * K + kb + schunk;
        const unsigned short* gb = W + (size_t)(n0 + srow) * K + kb + schunk;
        short8 a0 = *(const short8*)ga;
        short8 a1 = *(const short8*)(ga + (size_t)64 * K);
        short8 b0 = *(const short8*)gb;
        short8 b1 = *(const short8*)(gb + (size_t)64 * K);
        __syncthreads();
        *(short8*)&As[srow * LP + schunk]        = a0;
        *(short8*)&As[(srow + 64) * LP + schunk] = a1;
        *(short8*)&Bs[srow * LP + schunk]        = b0;
        *(short8*)&Bs[(srow + 64) * LP + schunk] = b1;
        __syncthreads();

        short8 af[4], bf[4];
#pragma unroll
        for (int mi = 0; mi < 4; ++mi)
            af[mi] = *(const short8*)&As[(wm + 16 * mi + fr) * LP + quad * 8];
#pragma unroll
        for (int ni = 0; ni < 4; ++ni)
            bf[ni] = *(const short8*)&Bs[(wn + 16 * ni + fr) * LP + quad * 8];
#pragma unroll
        for (int mi = 0; mi < 4; ++mi)
#pragma unroll
            for (int ni = 0; ni < 4; ++ni)
                acc[mi][ni] = __builtin_amdgcn_mfma_f32_16x16x32_bf16(
                    af[mi], bf[ni], acc[mi][ni], 0, 0, 0);
    }

    if (mode == 0) {
#pragma unroll
        for (int ni = 0; ni < 4; ++ni) {
            int cc = n0 + wn + 16 * ni + fr;
            float bv = bias[cc];
#pragma unroll
            for (int mi = 0; mi < 4; ++mi) {
                int rbase = m0 + wm + 16 * mi + quad * 4;
#pragma unroll
                for (int r = 0; r < 4; ++r)
                    C[(size_t)(rbase + r) * N + cc] = acc[mi][ni][r] + bv;
            }
        }
    } else if (mode == 1) {
#pragma unroll
        for (int ni = 0; ni < 4; ++ni) {
            int cc = n0 + wn + 16 * ni + fr;
            int h = cc >> 6, d = cc & 63;
            float bv = bias[cc];
#pragma unroll
            for (int mi = 0; mi < 4; ++mi) {
                int rbase = m0 + wm + 16 * mi + quad * 4;
                int b = rbase >> 10, q0 = rbase & 1023;
#pragma unroll
                for (int r = 0; r < 4; ++r) {
                    float val = acc[mi][ni][r] + bv;
                    unsigned short hi = f2bf(val);
                    unsigned short lo = f2bf(val - bf2f(hi));
                    size_t o = (((size_t)b * Hn + h) * Sn + q0 + r) * DKn + d;
                    Chi[o] = hi; Clo[o] = lo;
                }
            }
        }
    } else {  // mode 2: V^T bf16
#pragma unroll
        for (int ni = 0; ni < 4; ++ni) {
            int cc = n0 + wn + 16 * ni + fr;
            int h = cc >> 6, d = cc & 63;
            float bv = bias[cc];
#pragma unroll
            for (int mi = 0; mi < 4; ++mi) {
                int rbase = m0 + wm + 16 * mi + quad * 4;
                int b = rbase >> 10, tok0 = rbase & 1023;
                ushort4 o4;
#pragma unroll
                for (int r = 0; r < 4; ++r) o4[r] = f2bf(acc[mi][ni][r] + bv);
                *(ushort4*)&Chi[(((size_t)b * Hn + h) * DKn + d) * Sn + tok0] = o4;
            }
        }
    }
}

// ---------------------------------------------------------------------------
// Rk[u][d] hi/lo = split-bf16 of embK[clip(u-1024,+-MRP)+MRP][d], u in [0,RKU)
// ---------------------------------------------------------------------------
__global__ __launch_bounds__(256) void build_rk(
    const float* __restrict__ embK, unsigned short* __restrict__ Rh,
    unsigned short* __restrict__ Rl)
{
    int i = (blockIdx.x * 256 + threadIdx.x) * 4;
    if (i >= RKU * DKn) return;
    int u = i >> 6, d0 = i & 63;
    int t = min(max(u - 1024, -MRPn), MRPn);
    float4 v = *(const float4*)&embK[(size_t)(t + MRPn) * DKn + d0];
    ushort4 hi, lo;
    hi.x = f2bf(v.x); lo.x = f2bf(v.x - bf2f(hi.x));
    hi.y = f2bf(v.y); lo.y = f2bf(v.y - bf2f(hi.y));
    hi.z = f2bf(v.z); lo.z = f2bf(v.z - bf2f(hi.z));
    hi.w = f2bf(v.w); lo.w = f2bf(v.w - bf2f(hi.w));
    *(ushort4*)&Rh[i] = hi;
    *(ushort4*)&Rl[i] = lo;
}

// ---------------------------------------------------------------------------
// E2V[d][u] = bf16(embV[clip(u-1024,-MRP,MRP)+MRP, d]), u in [0,2048)
// ---------------------------------------------------------------------------
__global__ __launch_bounds__(256) void build_e2v(
    const float* __restrict__ embV, unsigned short* __restrict__ E2V)
{
    int i = (blockIdx.x * 256 + threadIdx.x) * 8;
    int d = i >> 11, u0 = i & 2047;
    short8 o;
#pragma unroll
    for (int e = 0; e < 8; ++e) {
        int t = u0 + e - 1024;
        t = min(max(t, -MRPn), MRPn);
        o[e] = (short)f2bf(embV[(size_t)(t + MRPn) * DKn + d]);
    }
    *(short8*)&E2V[i] = o;
}

// ---------------------------------------------------------------------------
// MFMA logits: L[bh,q,k] = Q.K^T + shear(Q.Rk^T)
// Per block: one bh, 64-q tile, loop over 16 k-tiles of 64.
// fp32-accurate via 3-term bf16 split (hi*hi + lo*hi + hi*lo).
// Rel term computed in u = k-q+1024 coords (plain GEMM vs Rk band), sheared
// back through a 33 KB LDS buffer in the epilogue.
// All A/B fragments read directly from global (L1/L2-resident); XCD swizzle
// groups the 16 q-tiles of each bh on one XCD for K/Q L2 locality.
// ---------------------------------------------------------------------------
__global__ __launch_bounds__(256) void logits_mfma(
    const unsigned short* __restrict__ Qh, const unsigned short* __restrict__ Ql,
    const unsigned short* __restrict__ Kh, const unsigned short* __restrict__ Kl,
    const unsigned short* __restrict__ Rh, const unsigned short* __restrict__ Rl,
    float* __restrict__ L)
{
    __shared__ float RelU[64][132];
    const int tid = threadIdx.x;
    const int lane = tid & 63, wave = tid >> 6;
    const int wy = wave >> 1, wx = wave & 1;
    const int fr = lane & 15, quad = lane >> 4;
    const int n = blockIdx.x;
    const int virt = (n & 7) * 128 + (n >> 3);   // 8 bh per XCD
    const int bh = virt >> 4, q0 = (virt & 15) * 64;

    const unsigned short* qbh = Qh + ((size_t)bh * Sn + q0) * DKn;
    const unsigned short* qbl = Ql + ((size_t)bh * Sn + q0) * DKn;

    short8 aH[2][2], aL[2][2];   // [kb][mi] — Q tile fragments, fixed per block
#pragma unroll
    for (int kbi = 0; kbi < 2; ++kbi)
#pragma unroll
        for (int mi = 0; mi < 2; ++mi) {
            int off = (wy * 32 + 16 * mi + fr) * DKn + kbi * 32 + quad * 8;
            aH[kbi][mi] = *(const short8*)(qbh + off);
            aL[kbi][mi] = *(const short8*)(qbl + off);
        }

    for (int kt = 0; kt < 16; ++kt) {
        const int k0 = kt * 64;
        const unsigned short* kbh = Kh + ((size_t)bh * Sn + k0) * DKn;
        const unsigned short* kbl = Kl + ((size_t)bh * Sn + k0) * DKn;
        const int u0 = k0 - q0 + 961 + wx * 64;          // band base, in [1,1985]
        const unsigned short* rbh = Rh + (size_t)u0 * DKn;
        const unsigned short* rbl = Rl + (size_t)u0 * DKn;

        f32x4 acc[2][2], rel[2][4];
#pragma unroll
        for (int i = 0; i < 2; ++i)
#pragma unroll
            for (int j = 0; j < 2; ++j) acc[i][j] = (f32x4){0.f, 0.f, 0.f, 0.f};
#pragma unroll
        for (int i = 0; i < 2; ++i)
#pragma unroll
            for (int j = 0; j < 4; ++j) rel[i][j] = (f32x4){0.f, 0.f, 0.f, 0.f};

#pragma unroll
        for (int kbi = 0; kbi < 2; ++kbi) {
            short8 bKH[2], bKL[2], bRH[4], bRL[4];
#pragma unroll
            for (int ni = 0; ni < 2; ++ni) {
                int off = (wx * 32 + 16 * ni + fr) * DKn + kbi * 32 + quad * 8;
                bKH[ni] = *(const short8*)(kbh + off);
                bKL[ni] = *(const short8*)(kbl + off);
            }
#pragma unroll
            for (int ni = 0; ni < 4; ++ni) {
                int off = (16 * ni + fr) * DKn + kbi * 32 + quad * 8;
                bRH[ni] = *(const short8*)(rbh + off);
                bRL[ni] = *(const short8*)(rbl + off);
            }
#pragma unroll
            for (int mi = 0; mi < 2; ++mi)
#pragma unroll
                for (int ni = 0; ni < 2; ++ni) {
                    acc[mi][ni] = __builtin_amdgcn_mfma_f32_16x16x32_bf16(
                        aH[kbi][mi], bKH[ni], acc[mi][ni], 0, 0, 0);
                    acc[mi][ni] = __builtin_amdgcn_mfma_f32_16x16x32_bf16(
                        aL[kbi][mi], bKH[ni], acc[mi][ni], 0, 0, 0);
                    acc[mi][ni] = __builtin_amdgcn_mfma_f32_16x16x32_bf16(
                        aH[kbi][mi], bKL[ni], acc[mi][ni], 0, 0, 0);
                }
#pragma unroll
            for (int mi = 0; mi < 2; ++mi)
#pragma unroll
                for (int ni = 0; ni < 4; ++ni) {
                    rel[mi][ni] = __builtin_amdgcn_mfma_f32_16x16x32_bf16(
                        aH[kbi][mi], bRH[ni], rel[mi][ni], 0, 0, 0);
                    rel[mi][ni] = __builtin_amdgcn_mfma_f32_16x16x32_bf16(
                        aL[kbi][mi], bRH[ni], rel[mi][ni], 0, 0, 0);
                    rel[mi][ni] = __builtin_amdgcn_mfma_f32_16x16x32_bf16(
                        aH[kbi][mi], bRL[ni], rel[mi][ni], 0, 0, 0);
                }
        }

        // shear: RelU[q_local][u - u_base], then L[q,k] = acc + RelU[q][c-q+63]
#pragma unroll
        for (int mi = 0; mi < 2; ++mi)
#pragma unroll
            for (int ni = 0; ni < 4; ++ni)
#pragma unroll
                for (int r = 0; r < 4; ++r)
                    RelU[wy * 32 + 16 * mi + quad * 4 + r]
                        [wx * 64 + 16 * ni + fr] = rel[mi][ni][r];
        __syncthreads();
#pragma unroll
        for (int mi = 0; mi < 2; ++mi)
#pragma unroll
            for (int ni = 0; ni < 2; ++ni) {
                int c = wx * 32 + 16 * ni + fr;
#pragma unroll
                for (int r = 0; r < 4; ++r) {
                    int row = wy * 32 + 16 * mi + quad * 4 + r;
                    L[((size_t)bh * Sn + q0 + row) * Sn + k0 + c] =
                        acc[mi][ni][r] + RelU[row][c - row + 63];
                }
            }
        __syncthreads();
    }
}

// ---------------------------------------------------------------------------
// In-place row softmax over last dim (1024). One block (256 thr) per row.
// ---------------------------------------------------------------------------
__global__ __launch_bounds__(256) void softmax_kernel(float* __restrict__ Wt)
{
    __shared__ float red[4];
    const int tid = threadIdx.x;
    float* p = Wt + (size_t)blockIdx.x * Sn;
    float4 v = ((const float4*)p)[tid];

    float m = fmaxf(fmaxf(v.x, v.y), fmaxf(v.z, v.w));
#pragma unroll
    for (int o = 32; o > 0; o >>= 1) m = fmaxf(m, __shfl_down(m, o, 64));
    if ((tid & 63) == 0) red[tid >> 6] = m;
    __syncthreads();
    m = fmaxf(fmaxf(red[0], red[1]), fmaxf(red[2], red[3]));
    __syncthreads();

    float4 e;
    e.x = expf(v.x - m); e.y = expf(v.y - m);
    e.z = expf(v.z - m); e.w = expf(v.w - m);
    float s = e.x + e.y + e.z + e.w;
#pragma unroll
    for (int o = 32; o > 0; o >>= 1) s += __shfl_down(s, o, 64);
    if ((tid & 63) == 0) red[tid >> 6] = s;
    __syncthreads();
    s = red[0] + red[1] + red[2] + red[3];

    float inv = 1.0f / s;
    e.x *= inv; e.y *= inv; e.z *= inv; e.w *= inv;
    ((float4*)p)[tid] = e;
}

// ---------------------------------------------------------------------------
// MFMA AV: X[b,q,h*64+d] = sum_k W[q,k]*V[k,d] + sum_u Wsk[q,u]*E2V[u,d]
// ---------------------------------------------------------------------------
__global__ __launch_bounds__(256) void av_mfma(
    const float* __restrict__ Wt, const unsigned short* __restrict__ Vt,
    const unsigned short* __restrict__ E2V, unsigned short* __restrict__ Xbf)
{
    __shared__ unsigned short As[64 * LP];
    __shared__ unsigned short Bs[64 * LP];
    const int tid  = threadIdx.x;
    const int lane = tid & 63;
    const int wave = tid >> 6;
    const int q0 = blockIdx.x * 64;
    const int bh = blockIdx.y;
    const int b = bh >> 4, h = bh & 15;
    const int wm = (wave & 1) * 32;
    const int wn = (wave >> 1) * 32;
    const int fr = lane & 15, quad = lane >> 4;

    const float* Wrow = Wt + (size_t)bh * Sn * Sn;

    f32x4 acc[2][2];
#pragma unroll
    for (int i = 0; i < 2; ++i)
#pragma unroll
        for (int j = 0; j < 2; ++j) acc[i][j] = (f32x4){0.f, 0.f, 0.f, 0.f};

    const int ar = tid >> 3;
    const int ac = (tid & 7) * 4;
    const int br = tid >> 2;
    const int bc = (tid & 3) * 8;

    const unsigned short* vrow = Vt + ((size_t)bh * DKn + br) * Sn;

    // ---- phase 1: W @ V^T  (K = 1024) ----
    for (int kb = 0; kb < Sn; kb += 32) {
        short8 bv = *(const short8*)(vrow + kb + bc);
        float4 a0 = *(const float4*)&Wrow[(size_t)(q0 + ar) * Sn + kb + ac];
        float4 a1 = *(const float4*)&Wrow[(size_t)(q0 + ar + 32) * Sn + kb + ac];
        __syncthreads();
        ushort4 s0, s1;
        s0.x = f2bf(a0.x); s0.y = f2bf(a0.y); s0.z = f2bf(a0.z); s0.w = f2bf(a0.w);
        s1.x = f2bf(a1.x); s1.y = f2bf(a1.y); s1.z = f2bf(a1.z); s1.w = f2bf(a1.w);
        *(ushort4*)&As[ar * LP + ac]        = s0;
        *(ushort4*)&As[(ar + 32) * LP + ac] = s1;
        *(short8*)&Bs[br * LP + bc]         = bv;
        __syncthreads();

        short8 af[2], bfv[2];
#pragma unroll
        for (int mi = 0; mi < 2; ++mi)
            af[mi] = *(const short8*)&As[(wm + 16 * mi + fr) * LP + quad * 8];
#pragma unroll
        for (int ni = 0; ni < 2; ++ni)
            bfv[ni] = *(const short8*)&Bs[(wn + 16 * ni + fr) * LP + quad * 8];
#pragma unroll
        for (int mi = 0; mi < 2; ++mi)
#pragma unroll
            for (int ni = 0; ni < 2; ++ni)
                acc[mi][ni] = __builtin_amdgcn_mfma_f32_16x16x32_bf16(
                    af[mi], bfv[ni], acc[mi][ni], 0, 0, 0);
    }

    // ---- phase 2: Wsk @ E2V^T ----
    int lo = 1024 - q0 - 63; if (lo < 0) lo = 0; lo &= ~31;
    const int hi = 2047 - q0;
    for (int ub = lo; ub <= hi; ub += 32) {
        short8 bv = *(const short8*)&E2V[(size_t)br * 2048 + ub + bc];
        float fa[2][4];
#pragma unroll
        for (int p = 0; p < 2; ++p) {
            int q = q0 + ar + 32 * p;
            int k = q + ub + ac - 1024;
#pragma unroll
            for (int e = 0; e < 4; ++e) {
                int ke = k + e;
                fa[p][e] = ((unsigned)ke < 1024u) ? Wrow[(size_t)q * Sn + ke] : 0.f;
            }
        }
        __syncthreads();
        ushort4 s0, s1;
        s0.x = f2bf(fa[0][0]); s0.y = f2bf(fa[0][1]);
        s0.z = f2bf(fa[0][2]); s0.w = f2bf(fa[0][3]);
        s1.x = f2bf(fa[1][0]); s1.y = f2bf(fa[1][1]);
        s1.z = f2bf(fa[1][2]); s1.w = f2bf(fa[1][3]);
        *(ushort4*)&As[ar * LP + ac]        = s0;
        *(ushort4*)&As[(ar + 32) * LP + ac] = s1;
        *(short8*)&Bs[br * LP + bc]         = bv;
        __syncthreads();

        short8 af[2], bfv[2];
#pragma unroll
        for (int mi = 0; mi < 2; ++mi)
            af[mi] = *(const short8*)&As[(wm + 16 * mi + fr) * LP + quad * 8];
#pragma unroll
        for (int ni = 0; ni < 2; ++ni)
            bfv[ni] = *(const short8*)&Bs[(wn + 16 * ni + fr) * LP + quad * 8];
#pragma unroll
        for (int mi = 0; mi < 2; ++mi)
#pragma unroll
            for (int ni = 0; ni < 2; ++ni)
                acc[mi][ni] = __builtin_amdgcn_mfma_f32_16x16x32_bf16(
                    af[mi], bfv[ni], acc[mi][ni], 0, 0, 0);
    }

#pragma unroll
    for (int ni = 0; ni < 2; ++ni) {
        int d = wn + 16 * ni + fr;
#pragma unroll
        for (int mi = 0; mi < 2; ++mi) {
            int qb = q0 + wm + 16 * mi + quad * 4;
#pragma unroll
            for (int r = 0; r < 4; ++r)
                Xbf[(size_t)(b * Sn + qb + r) * Dn + h * DKn + d] =
                    f2bf(acc[mi][ni][r]);
        }
    }
}

// ---------------------------------------------------------------------------
extern "C" void kernel_launch(void* const* d_in, const int* in_sizes, int n_in,
                              void* d_out, int out_size, void* d_ws, size_t ws_size,
                              hipStream_t stream)
{
    const float* query = (const float*)d_in[0];
    const float* key   = (const float*)d_in[1];
    const float* value = (const float*)d_in[2];
    const float* Wq    = (const float*)d_in[3];
    const float* bq    = (const float*)d_in[4];
    const float* Wk    = (const float*)d_in[5];
    const float* bk    = (const float*)d_in[6];
    const float* Wv    = (const float*)d_in[7];
    const float* bv    = (const float*)d_in[8];
    const float* Wo    = (const float*)d_in[9];
    const float* bo    = (const float*)d_in[10];
    const float* embK  = (const float*)d_in[11];
    const float* embV  = (const float*)d_in[12];

    const size_t NTOK = (size_t)Bn * Sn;          // 4096
    const size_t PROJ = NTOK * Dn;                // 4,194,304
    const size_t WSZ  = (size_t)Dn * Dn;          // 1,048,576

    unsigned short* u16 = (unsigned short*)d_ws;
    unsigned short* Abf = u16;                    // bf16 [4096,1024] (reused)
    unsigned short* Wqb = Abf + PROJ;
    unsigned short* Wkb = Wqb + WSZ;
    unsigned short* Wvb = Wkb + WSZ;
    unsigned short* Wob = Wvb + WSZ;
    unsigned short* Qhi = Wob + WSZ;              // [64bh][1024q][64d]
    unsigned short* Qlo = Qhi + PROJ;
    unsigned short* Khi = Qlo + PROJ;
    unsigned short* Klo = Khi + PROJ;
    unsigned short* Vtb = Klo + PROJ;             // [64bh][64d][1024k]
    unsigned short* E2V = Vtb + PROJ;             // [64d][2048u]
    unsigned short* RkH = E2V + (size_t)DKn * 2048;   // [RKU][64]
    unsigned short* RkL = RkH + (size_t)RKU * DKn;

    float* outp = (float*)d_out;                  // [B,S,D]
    float* Wt   = outp + PROJ;                    // weights [B,H,S,S]

    const int CAST_W_GRID = (int)(WSZ / 4 / 256);
    const int CAST_A_GRID = (int)(PROJ / 4 / 256);
    dim3 gemmGrid(Dn / 128, (int)(NTOK / 128));   // (8, 32)

    build_e2v<<<64, 256, 0, stream>>>(embV, E2V);
    build_rk<<<(RKU * DKn / 4 + 255) / 256, 256, 0, stream>>>(embK, RkH, RkL);

    cast_f32_bf16<<<CAST_W_GRID, 256, 0, stream>>>(Wq, Wqb, (int)WSZ);
    cast_f32_bf16<<<CAST_W_GRID, 256, 0, stream>>>(Wk, Wkb, (int)WSZ);
    cast_f32_bf16<<<CAST_W_GRID, 256, 0, stream>>>(Wv, Wvb, (int)WSZ);
    cast_f32_bf16<<<CAST_W_GRID, 256, 0, stream>>>(Wo, Wob, (int)WSZ);

    cast_f32_bf16<<<CAST_A_GRID, 256, 0, stream>>>(query, Abf, (int)PROJ);
    gemm_bf16_mfma<<<gemmGrid, 256, 0, stream>>>(Abf, Wqb, bq, nullptr, Qhi, Qlo,
                                                 (int)NTOK, Dn, Dn, 1);
    cast_f32_bf16<<<CAST_A_GRID, 256, 0, stream>>>(key, Abf, (int)PROJ);
    gemm_bf16_mfma<<<gemmGrid, 256, 0, stream>>>(Abf, Wkb, bk, nullptr, Khi, Klo,
                                                 (int)NTOK, Dn, Dn, 1);
    cast_f32_bf16<<<CAST_A_GRID, 256, 0, stream>>>(value, Abf, (int)PROJ);
    gemm_bf16_mfma<<<gemmGrid, 256, 0, stream>>>(Abf, Wvb, bv, nullptr, Vtb, nullptr,
                                                 (int)NTOK, Dn, Dn, 2);

    logits_mfma<<<Bn * Hn * (Sn / 64), 256, 0, stream>>>(
        Qhi, Qlo, Khi, Klo, RkH, RkL, Wt);

    softmax_kernel<<<Bn * Hn * Sn, 256, 0, stream>>>(Wt);

    av_mfma<<<dim3(Sn / 64, Bn * Hn), 256, 0, stream>>>(Wt, Vtb, E2V, Abf);

    gemm_bf16_mfma<<<gemmGrid, 256, 0, stream>>>(Abf, Wob, bo, outp, nullptr, nullptr,
                                                 (int)NTOK, Dn, Dn, 0);
}